// Round 4
// baseline (330.163 us; speedup 1.0000x reference)
//
#include <hip/hip_runtime.h>
#include <hip/hip_bf16.h>

#define NN 100000      // nodes
#define NE 3200000     // edges
#define NF 256         // features

typedef __attribute__((ext_vector_type(8))) __bf16 bf16x8;
typedef __attribute__((ext_vector_type(4))) float  f32x4;
typedef __attribute__((ext_vector_type(4))) int    i32x4;
typedef __attribute__((ext_vector_type(2))) unsigned int u32x2;

static __device__ __forceinline__ float lo2f(unsigned int d) {
    union { unsigned int i; float f; } c; c.i = d << 16; return c.f;
}
static __device__ __forceinline__ float hi2f(unsigned int d) {
    union { unsigned int i; float f; } c; c.i = d & 0xffff0000u; return c.f;
}

// ---- W -> per-lane MFMA B-fragments (bf16), same k-map as A-build below ----
__global__ __launch_bounds__(256) void prep_w(const float* __restrict__ w,
                                              __bf16* __restrict__ wfrag) {
    const int t = blockIdx.x * 256 + threadIdx.x;   // 8192 total
    const int lane = t & 63;
    const int nf   = (t >> 6) & 15;
    const int ks   = t >> 10;
    const int col  = nf * 16 + (lane & 15);
    const int k0   = ks * 32 + (lane >> 4) * 8;
    bf16x8 v;
#pragma unroll
    for (int j = 0; j < 8; ++j) v[j] = (__bf16)w[(k0 + j) * NF + col];
    reinterpret_cast<bf16x8*>(wfrag)[t] = v;
}

// ---- support = x @ W via mfma_f32_16x16x32_bf16; 5 waves x 16 rows/block ----
__global__ __launch_bounds__(320) void gemm_mfma(const float* __restrict__ x,
                                                 const __bf16* __restrict__ wfrag,
                                                 __bf16* __restrict__ support) {
    const int wv   = threadIdx.x >> 6;
    const int lane = threadIdx.x & 63;
    const int row0 = blockIdx.x * 80 + wv * 16;

    f32x4 acc[16];
#pragma unroll
    for (int nf = 0; nf < 16; ++nf) acc[nf] = (f32x4){0.f, 0.f, 0.f, 0.f};

    const float* xp = x + (size_t)(row0 + (lane & 15)) * NF + ((lane >> 4) << 3);
    const bf16x8* wf = reinterpret_cast<const bf16x8*>(wfrag);

#pragma unroll
    for (int ks = 0; ks < 8; ++ks) {
        const f32x4 a0 = __builtin_nontemporal_load(
            reinterpret_cast<const f32x4*>(xp + ks * 32));
        const f32x4 a1 = __builtin_nontemporal_load(
            reinterpret_cast<const f32x4*>(xp + ks * 32 + 4));
        bf16x8 af;
        af[0] = (__bf16)a0.x; af[1] = (__bf16)a0.y;
        af[2] = (__bf16)a0.z; af[3] = (__bf16)a0.w;
        af[4] = (__bf16)a1.x; af[5] = (__bf16)a1.y;
        af[6] = (__bf16)a1.z; af[7] = (__bf16)a1.w;
#pragma unroll
        for (int nf = 0; nf < 16; ++nf) {
            const bf16x8 bfr = wf[(ks * 16 + nf) * 64 + lane];
            acc[nf] = __builtin_amdgcn_mfma_f32_16x16x32_bf16(af, bfr, acc[nf], 0, 0, 0);
        }
    }

    // C/D: col = lane&15, row = (lane>>4)*4 + reg  (m89-verified)
    const int crow = row0 + ((lane >> 4) << 2);
    const int ccol = lane & 15;
#pragma unroll
    for (int nf = 0; nf < 16; ++nf) {
#pragma unroll
        for (int r = 0; r < 4; ++r)
            support[(size_t)(crow + r) * NF + nf * 16 + ccol] = (__bf16)acc[nf][r];
    }
}

// ---- CSR row pointers from sorted edge_row (int32) ----
__global__ void build_rowptr(const int* __restrict__ erow,
                             int* __restrict__ rowptr) {
    int e = blockIdx.x * blockDim.x + threadIdx.x;
    if (e >= NE) return;
    int r    = erow[e];
    int prev = (e == 0) ? -1 : erow[e - 1];
    for (int q = prev + 1; q <= r; ++q) rowptr[q] = e;
    if (e == NE - 1) {
        for (int q = r + 1; q <= NN; ++q) rowptr[q] = NE;
    }
}

// ---- spmm: one wave per row; chunk-of-8 pipelined gathers ----
__global__ __launch_bounds__(256) void spmm(const unsigned short* __restrict__ sp,
                                            const int* __restrict__ rowptr,
                                            const int* __restrict__ ecol,
                                            const float* __restrict__ eval,
                                            const float* __restrict__ bias,
                                            float* __restrict__ out) {
    const int wave = threadIdx.x >> 6;
    const int lane = threadIdx.x & 63;
    const int row  = blockIdx.x * 4 + wave;

    const int s = rowptr[row];
    const int e = rowptr[row + 1];

    // lane owns 4 consecutive bf16 features: byte offset lane*8 within a row
    const char* base = reinterpret_cast<const char*>(sp) + lane * 8;

    float a0 = 0.f, a1 = 0.f, a2 = 0.f, a3 = 0.f;

#define ACC(g, v)                                        \
    do {                                                 \
        a0 = fmaf((v), lo2f((g).x), a0);                 \
        a1 = fmaf((v), hi2f((g).x), a1);                 \
        a2 = fmaf((v), lo2f((g).y), a2);                 \
        a3 = fmaf((v), hi2f((g).y), a3);                 \
    } while (0)

    int i = s;
    // peel to 4-aligned edge index (<=3 edges)
    while (i < e && (i & 3)) {
        const int   c = ecol[i];
        const float v = eval[i];
        const u32x2 g = *reinterpret_cast<const u32x2*>(base + ((size_t)c << 9));
        ACC(g, v);
        ++i;
    }
    // main: chunks of 8 edges, 8 gathers in flight
    for (; i + 8 <= e; i += 8) {
        const i32x4 c0 = __builtin_nontemporal_load(reinterpret_cast<const i32x4*>(ecol + i));
        const i32x4 c1 = __builtin_nontemporal_load(reinterpret_cast<const i32x4*>(ecol + i + 4));
        const f32x4 v0 = __builtin_nontemporal_load(reinterpret_cast<const f32x4*>(eval + i));
        const f32x4 v1 = __builtin_nontemporal_load(reinterpret_cast<const f32x4*>(eval + i + 4));
        const u32x2 g0 = *reinterpret_cast<const u32x2*>(base + ((size_t)c0.x << 9));
        const u32x2 g1 = *reinterpret_cast<const u32x2*>(base + ((size_t)c0.y << 9));
        const u32x2 g2 = *reinterpret_cast<const u32x2*>(base + ((size_t)c0.z << 9));
        const u32x2 g3 = *reinterpret_cast<const u32x2*>(base + ((size_t)c0.w << 9));
        const u32x2 g4 = *reinterpret_cast<const u32x2*>(base + ((size_t)c1.x << 9));
        const u32x2 g5 = *reinterpret_cast<const u32x2*>(base + ((size_t)c1.y << 9));
        const u32x2 g6 = *reinterpret_cast<const u32x2*>(base + ((size_t)c1.z << 9));
        const u32x2 g7 = *reinterpret_cast<const u32x2*>(base + ((size_t)c1.w << 9));
        ACC(g0, v0.x); ACC(g1, v0.y); ACC(g2, v0.z); ACC(g3, v0.w);
        ACC(g4, v1.x); ACC(g5, v1.y); ACC(g6, v1.z); ACC(g7, v1.w);
    }
    // tail: clamped batch (<=7 real edges, padded with v=0)
    if (i < e) {
        const int n = e - i;
        int   cj[8];
        float vj[8];
#pragma unroll
        for (int j = 0; j < 8; ++j) {
            const int k = i + (j < n ? j : n - 1);
            cj[j] = ecol[k];
            vj[j] = (j < n) ? eval[k] : 0.f;
        }
        u32x2 g[8];
#pragma unroll
        for (int j = 0; j < 8; ++j)
            g[j] = *reinterpret_cast<const u32x2*>(base + ((size_t)cj[j] << 9));
#pragma unroll
        for (int j = 0; j < 8; ++j) ACC(g[j], vj[j]);
    }
#undef ACC

    const f32x4 b4 = *reinterpret_cast<const f32x4*>(bias + lane * 4);
    f32x4 o;
    o.x = a0 + b4.x; o.y = a1 + b4.y; o.z = a2 + b4.z; o.w = a3 + b4.w;
    __builtin_nontemporal_store(o, reinterpret_cast<f32x4*>(out + (size_t)row * NF + lane * 4));
}

extern "C" void kernel_launch(void* const* d_in, const int* in_sizes, int n_in,
                              void* d_out, int out_size, void* d_ws, size_t ws_size,
                              hipStream_t stream) {
    const float* x    = (const float*)d_in[0];
    const int*   erow = (const int*)d_in[1];
    const int*   ecol = (const int*)d_in[2];
    const float* eval = (const float*)d_in[3];
    const float* w    = (const float*)d_in[4];
    const float* bias = (const float*)d_in[5];
    float*       out  = (float*)d_out;

    __bf16* support = (__bf16*)d_ws;                                   // 51,200,000 B
    int*    rowptr  = (int*)((char*)d_ws + 51200000);                  // 400,004 B
    __bf16* wfrag   = (__bf16*)((char*)d_ws + 51600016);               // 131,072 B

    prep_w<<<32, 256, 0, stream>>>(w, wfrag);
    build_rowptr<<<(NE + 255) / 256, 256, 0, stream>>>(erow, rowptr);
    gemm_mfma<<<NN / 80, 320, 0, stream>>>(x, wfrag, support);
    spmm<<<NN / 4, 256, 0, stream>>>(
        reinterpret_cast<const unsigned short*>(support), rowptr, ecol, eval, bias, out);
}